// Round 5
// baseline (25.345 us; speedup 1.0000x reference)
//
#include <hip/hip_runtime.h>
#include <math.h>

// out[b,s,d] = emb_table[input_x[b,s], d] * 32 + pe[s,d]
// pe[s,2j] = sin(s*10000^(-2j/1024)), pe[s,2j+1] = cos(same)
// VOCAB=50257, D=1024, B=4, S=4096
#define SEQ_LEN 4096
#define DMODEL  1024
#define ROWS    4     // rows (tokens) per block

typedef float f32x4 __attribute__((ext_vector_type(4)));

__global__ __launch_bounds__(256) void TokenEmbedding_kernel(
    const int* __restrict__ tok,   // [B*S]
    const float* __restrict__ emb, // [VOCAB, D]
    float* __restrict__ out)       // [B*S, D]
{
    const int bs0 = blockIdx.x * ROWS;
    const int d0  = threadIdx.x << 2;   // 4 floats/thread, 256 thr = 1024 = D

    // Tokens are block-uniform -> scalar loads; issue all up front.
    int t[ROWS];
#pragma unroll
    for (int r = 0; r < ROWS; ++r) t[r] = tok[bs0 + r];

    // Issue all ROWS gathers back-to-back: 4 outstanding dwordx4 per lane.
    f32x4 e[ROWS];
#pragma unroll
    for (int r = 0; r < ROWS; ++r)
        e[r] = *reinterpret_cast<const f32x4*>(emb + (long)t[r] * DMODEL + d0);

    // Row-invariant frequencies (depend only on d0): computed once.
    //   rev_freq(i) = 10000^(-i/1024) / (2*pi) = exp2(-i*log2(1e4)/1024 + log2(1/2pi))
    const float NEG_L2_10K_OVER_D = -13.287712379549609f / 1024.0f;
    const float L2_INV2PI         = -2.6514961294723187f; // log2(1/(2*pi))
    const float rf0 = __builtin_exp2f(fmaf((float)d0,       NEG_L2_10K_OVER_D, L2_INV2PI));
    const float rf1 = __builtin_exp2f(fmaf((float)(d0 + 2), NEG_L2_10K_OVER_D, L2_INV2PI));

#pragma unroll
    for (int r = 0; r < ROWS; ++r) {
        const int   bs = bs0 + r;
        const float sp = (float)(bs & (SEQ_LEN - 1));   // position in sequence

        float r0 = sp * rf0; r0 -= floorf(r0);   // revolutions, v_fract
        float r1 = sp * rf1; r1 -= floorf(r1);

#if __has_builtin(__builtin_amdgcn_sinf) && __has_builtin(__builtin_amdgcn_cosf)
        const float s0 = __builtin_amdgcn_sinf(r0);  // v_sin_f32: sin(2*pi*r)
        const float c0 = __builtin_amdgcn_cosf(r0);
        const float s1 = __builtin_amdgcn_sinf(r1);
        const float c1 = __builtin_amdgcn_cosf(r1);
#else
        const float TWO_PI = 6.283185307179586f;
        const float s0 = sinf(r0 * TWO_PI), c0 = cosf(r0 * TWO_PI);
        const float s1 = sinf(r1 * TWO_PI), c1 = cosf(r1 * TWO_PI);
#endif

        f32x4 v;
        v.x = fmaf(e[r].x, 32.0f, s0);   // sqrt(1024) == 32 exactly
        v.y = fmaf(e[r].y, 32.0f, c0);
        v.z = fmaf(e[r].z, 32.0f, s1);
        v.w = fmaf(e[r].w, 32.0f, c1);

        // Write-once output: non-temporal store keeps table lines in L2/L3.
        __builtin_nontemporal_store(
            v, reinterpret_cast<f32x4*>(out + (long)bs * DMODEL + d0));
    }
}

extern "C" void kernel_launch(void* const* d_in, const int* in_sizes, int n_in,
                              void* d_out, int out_size, void* d_ws, size_t ws_size,
                              hipStream_t stream) {
    const int*   tok = (const int*)d_in[0];    // input_x, [4*4096] int32
    const float* emb = (const float*)d_in[1];  // emb_table, [50257*1024] f32
    float*       out = (float*)d_out;          // [4*4096*1024] f32

    const int n_tok  = in_sizes[0];            // 16384 rows (divisible by ROWS)
    dim3 grid(n_tok / ROWS), block(256);
    TokenEmbedding_kernel<<<grid, block, 0, stream>>>(tok, emb, out);
}